// Round 1
// baseline (192.241 us; speedup 1.0000x reference)
//
#include <hip/hip_runtime.h>
#include <stdint.h>

#define NLEV   256
#define DIST   5
#define NB     64
#define NH     512
#define NW     512
#define PLANE  (NH*NW)            // 262144
#define NPAIRS (NH*(NW-DIST))     // 259584

// ---------------------------------------------------------------------------
// K1: img [64,3,512,512] f32 -> packed gray indices, 4 pixels per u32 word.
// Exactly replicates: q = clip(floor(img*255),0,255);
//                     gray = 0.299*q0 + 0.587*q1 + 0.114*q2;
//                     idx  = clip(round_half_even(gray),0,255)
// ---------------------------------------------------------------------------
__global__ __launch_bounds__(256) void k_gray(const float* __restrict__ img,
                                              uint32_t* __restrict__ gray) {
    int n4   = blockIdx.x * 256 + threadIdx.x;   // one thread per 4 pixels
    int b    = n4 >> 16;                         // 65536 groups of 4 per batch
    int rem4 = n4 & 65535;
    const float4* rp = (const float4*)(img + (size_t)(b*3+0)*PLANE) + rem4;
    const float4* gp = (const float4*)(img + (size_t)(b*3+1)*PLANE) + rem4;
    const float4* bp = (const float4*)(img + (size_t)(b*3+2)*PLANE) + rem4;
    float4 r = *rp, g = *gp, bl = *bp;
    float rr[4] = {r.x, r.y, r.z, r.w};
    float gg[4] = {g.x, g.y, g.z, g.w};
    float bb[4] = {bl.x, bl.y, bl.z, bl.w};
    uint32_t out = 0;
#pragma unroll
    for (int k = 0; k < 4; ++k) {
        float qr = fminf(fmaxf(floorf(__fmul_rn(rr[k], 255.0f)), 0.0f), 255.0f);
        float qg = fminf(fmaxf(floorf(__fmul_rn(gg[k], 255.0f)), 0.0f), 255.0f);
        float qb = fminf(fmaxf(floorf(__fmul_rn(bb[k], 255.0f)), 0.0f), 255.0f);
        float gy = __fadd_rn(__fadd_rn(__fmul_rn(0.299f, qr),
                                       __fmul_rn(0.587f, qg)),
                             __fmul_rn(0.114f, qb));
        int gi = (int)rintf(gy);                 // round half to even == jnp.round
        gi = gi < 0 ? 0 : (gi > 255 ? 255 : gi);
        out |= ((uint32_t)gi) << (8 * k);
    }
    gray[(size_t)b * 65536 + rem4] = out;
}

// ---------------------------------------------------------------------------
// K2: per-(batch, i-quarter[, row-part]) histogram in 64KB LDS, no global
// atomics. blockIdx.x = part*256 + b*4 + q. Each WG scans its rows of the
// batch and bins only pairs with i in [q*64, q*64+64).
// hist layout: [part][b][256*256] u32.
// ---------------------------------------------------------------------------
__global__ __launch_bounds__(256) void k_hist(const uint32_t* __restrict__ gray,
                                              uint32_t* __restrict__ hist,
                                              int nparts) {
    __shared__ uint32_t lh[64 * 256];            // 64 KB
    int bid  = blockIdx.x;
    int q    = bid & 3;
    int b    = (bid >> 2) & 63;
    int part = bid >> 8;
    int t    = threadIdx.x;

    for (int k = t; k < 64 * 256; k += 256) lh[k] = 0;
    __syncthreads();

    int rows_per_part = NH / nparts;
    int row0 = part * rows_per_part;
    int nseg = rows_per_part * 32;               // 32 16-byte segments per row

    const uint32_t* gb = gray + (size_t)b * 65536;

    for (int seg = t; seg < nseg; seg += 256) {
        int row = row0 + (seg >> 5);
        int s   = seg & 31;
        int base = row * 128 + s * 4;            // dword index within batch
        uint4 wv = *(const uint4*)(gb + base);
        uint32_t Wd[6];
        Wd[0] = wv.x; Wd[1] = wv.y; Wd[2] = wv.z; Wd[3] = wv.w;
        if (s < 31) { Wd[4] = gb[base + 4]; Wd[5] = gb[base + 5]; }
        else        { Wd[4] = 0;            Wd[5] = 0; }
        int cbase = s * 16;
#pragma unroll
        for (int k = 0; k < 4; ++k) {
            uint32_t iw = Wd[k];
            uint32_t jw = (Wd[k + 1] >> 8) | (Wd[k + 2] << 24);
#pragma unroll
            for (int m = 0; m < 4; ++m) {
                int c = cbase + 4 * k + m;
                uint32_t i = (iw >> (8 * m)) & 255u;
                uint32_t j = (jw >> (8 * m)) & 255u;
                if (c < (NW - DIST) && (i >> 6) == (uint32_t)q)
                    atomicAdd(&lh[(i & 63u) * 256u + j], 1u);
            }
        }
    }
    __syncthreads();

    uint32_t* hout = hist + ((size_t)(part * NB + b)) * 65536 + (size_t)q * 64 * 256;
    for (int k = t; k < 64 * 256; k += 256) hout[k] = lh[k];
}

// ---------------------------------------------------------------------------
// K3: one WG per batch. Symmetrize on the fly (c_ij + c_ji), accumulate the
// 9 moments in f64, block-reduce, thread 0 computes features + normalize +
// floor-quantize and writes out[b][3][5].
// ---------------------------------------------------------------------------
__global__ __launch_bounds__(256) void k_feat(const uint32_t* __restrict__ hist,
                                              float* __restrict__ out,
                                              int nparts) {
    int b = blockIdx.x;
    int t = threadIdx.x;

    double a_con = 0.0, a_dis = 0.0, a_hom = 0.0, a_e2 = 0.0;
    double a_si = 0.0, a_sj = 0.0, a_sii = 0.0, a_sjj = 0.0, a_sij = 0.0;

    for (int bin = t; bin < 65536; bin += 256) {
        int i = bin >> 8, j = bin & 255;
        uint32_t cij = 0, cji = 0;
        for (int p = 0; p < nparts; ++p) {
            const uint32_t* hp = hist + ((size_t)(p * NB + b)) * 65536;
            cij += hp[bin];
            cji += hp[(j << 8) + i];
        }
        uint32_t su = cij + cji;
        if (su) {
            double s  = (double)su;
            double di = (double)(i - j);
            double dd = di * di;
            a_con += s * dd;
            a_dis += s * fabs(di);
            a_hom += s / (1.0 + dd);
            a_e2  += s * s;
            a_si  += s * (double)i;
            a_sj  += s * (double)j;
            a_sii += s * (double)i * (double)i;
            a_sjj += s * (double)j * (double)j;
            a_sij += s * (double)i * (double)j;
        }
    }

    // wave reduce (64 lanes) then cross-wave via LDS
    double acc[9] = {a_con, a_dis, a_hom, a_e2, a_si, a_sj, a_sii, a_sjj, a_sij};
#pragma unroll
    for (int a = 0; a < 9; ++a) {
#pragma unroll
        for (int off = 32; off; off >>= 1)
            acc[a] += __shfl_down(acc[a], off, 64);
    }
    __shared__ double sred[9][4];
    int wid = t >> 6, lane = t & 63;
    if (lane == 0) {
#pragma unroll
        for (int a = 0; a < 9; ++a) sred[a][wid] = acc[a];
    }
    __syncthreads();

    if (t == 0) {
        double v[9];
#pragma unroll
        for (int a = 0; a < 9; ++a)
            v[a] = sred[a][0] + sred[a][1] + sred[a][2] + sred[a][3];

        const double total = 2.0 * (double)NPAIRS;   // symmetrized sum
        double contrast = v[0] / total;
        double dissim   = v[1] / total;
        double homog    = v[2] / total;
        double energy   = sqrt(v[3] / (total * total));
        double mu_i = v[4] / total, mu_j = v[5] / total;
        double var_i = v[6] / total - mu_i * mu_i;
        double var_j = v[7] / total - mu_j * mu_j;
        double cov   = v[8] / total - mu_i * mu_j;
        double sd    = sqrt(var_i * var_j);
        double corr  = (sd < 1e-15) ? 1.0 : cov / fmax(sd, 1e-15);

        float f[5] = {(float)contrast, (float)dissim, (float)homog,
                      (float)energy, (float)corr};
        float mn = f[0], mx = f[0];
#pragma unroll
        for (int k = 1; k < 5; ++k) { mn = fminf(mn, f[k]); mx = fmaxf(mx, f[k]); }
        float rng = mx - mn;
#pragma unroll
        for (int k = 0; k < 5; ++k) {
            float fn = (f[k] - mn) / rng;
            float q8 = floorf(__fmul_rn(fn, 255.0f));
            float val = q8 / 255.0f;
            out[b * 15 + 0 * 5 + k] = val;
            out[b * 15 + 1 * 5 + k] = val;
            out[b * 15 + 2 * 5 + k] = val;
        }
    }
}

// ---------------------------------------------------------------------------
extern "C" void kernel_launch(void* const* d_in, const int* in_sizes, int n_in,
                              void* d_out, int out_size, void* d_ws, size_t ws_size,
                              hipStream_t stream) {
    const float* img = (const float*)d_in[0];
    float* out = (float*)d_out;

    uint32_t* gray = (uint32_t*)d_ws;                         // 16 MB
    uint32_t* hist = (uint32_t*)((char*)d_ws + ((size_t)1 << 24));

    int nparts = (ws_size >= ((size_t)3 << 24)) ? 2 : 1;      // 48MB -> row-split 2

    k_gray<<<16384, 256, 0, stream>>>(img, gray);
    k_hist<<<256 * nparts, 256, 0, stream>>>(gray, hist, nparts);
    k_feat<<<NB, 256, 0, stream>>>(hist, out, nparts);
}

// Round 3
// 92.552 us; speedup vs baseline: 2.0771x; 2.0771x over previous
//
#include <hip/hip_runtime.h>
#include <stdint.h>

#define NLEV   256
#define DIST   5
#define NB     64
#define NH     512
#define NW     512
#define PLANE  (NH*NW)            // 262144
#define NPAIRS (NH*(NW-DIST))     // 259584

// ---------------------------------------------------------------------------
// K1: img [64,3,512,512] f32 -> packed gray indices, 4 pixels per u32 word.
// ---------------------------------------------------------------------------
__global__ __launch_bounds__(256) void k_gray(const float* __restrict__ img,
                                              uint32_t* __restrict__ gray) {
    int n4   = blockIdx.x * 256 + threadIdx.x;   // one thread per 4 pixels
    int b    = n4 >> 16;                         // 65536 groups of 4 per batch
    int rem4 = n4 & 65535;
    const float4* rp = (const float4*)(img + (size_t)(b*3+0)*PLANE) + rem4;
    const float4* gp = (const float4*)(img + (size_t)(b*3+1)*PLANE) + rem4;
    const float4* bp = (const float4*)(img + (size_t)(b*3+2)*PLANE) + rem4;
    float4 r = *rp, g = *gp, bl = *bp;
    float rr[4] = {r.x, r.y, r.z, r.w};
    float gg[4] = {g.x, g.y, g.z, g.w};
    float bb[4] = {bl.x, bl.y, bl.z, bl.w};
    uint32_t out = 0;
#pragma unroll
    for (int k = 0; k < 4; ++k) {
        float qr = fminf(fmaxf(floorf(__fmul_rn(rr[k], 255.0f)), 0.0f), 255.0f);
        float qg = fminf(fmaxf(floorf(__fmul_rn(gg[k], 255.0f)), 0.0f), 255.0f);
        float qb = fminf(fmaxf(floorf(__fmul_rn(bb[k], 255.0f)), 0.0f), 255.0f);
        float gy = __fadd_rn(__fadd_rn(__fmul_rn(0.299f, qr),
                                       __fmul_rn(0.587f, qg)),
                             __fmul_rn(0.114f, qb));
        int gi = (int)rintf(gy);                 // round half to even == jnp.round
        gi = gi < 0 ? 0 : (gi > 255 ? 255 : gi);
        out |= ((uint32_t)gi) << (8 * k);
    }
    gray[(size_t)b * 65536 + rem4] = out;
}

// ---------------------------------------------------------------------------
// K2: per-(batch, i-quarter[, row-part]) histogram in 64KB LDS, no global
// atomics. hist layout: [part][b][256*256] u32.
// ---------------------------------------------------------------------------
__global__ __launch_bounds__(256) void k_hist(const uint32_t* __restrict__ gray,
                                              uint32_t* __restrict__ hist,
                                              int nparts) {
    __shared__ uint32_t lh[64 * 256];            // 64 KB
    int bid  = blockIdx.x;
    int q    = bid & 3;
    int b    = (bid >> 2) & 63;
    int part = bid >> 8;
    int t    = threadIdx.x;

    for (int k = t; k < 64 * 256; k += 256) lh[k] = 0;
    __syncthreads();

    int rows_per_part = NH / nparts;
    int row0 = part * rows_per_part;
    int nseg = rows_per_part * 32;               // 32 16-byte segments per row

    const uint32_t* gb = gray + (size_t)b * 65536;

    for (int seg = t; seg < nseg; seg += 256) {
        int row = row0 + (seg >> 5);
        int s   = seg & 31;
        int base = row * 128 + s * 4;            // dword index within batch
        uint4 wv = *(const uint4*)(gb + base);
        uint32_t Wd[6];
        Wd[0] = wv.x; Wd[1] = wv.y; Wd[2] = wv.z; Wd[3] = wv.w;
        if (s < 31) { Wd[4] = gb[base + 4]; Wd[5] = gb[base + 5]; }
        else        { Wd[4] = 0;            Wd[5] = 0; }
        int cbase = s * 16;
#pragma unroll
        for (int k = 0; k < 4; ++k) {
            uint32_t iw = Wd[k];
            uint32_t jw = (Wd[k + 1] >> 8) | (Wd[k + 2] << 24);
#pragma unroll
            for (int m = 0; m < 4; ++m) {
                int c = cbase + 4 * k + m;
                uint32_t i = (iw >> (8 * m)) & 255u;
                uint32_t j = (jw >> (8 * m)) & 255u;
                if (c < (NW - DIST) && (i >> 6) == (uint32_t)q)
                    atomicAdd(&lh[(i & 63u) * 256u + j], 1u);
            }
        }
    }
    __syncthreads();

    uint32_t* hout = hist + ((size_t)(part * NB + b)) * 65536 + (size_t)q * 64 * 256;
    for (int k = t; k < 64 * 256; k += 256) hout[k] = lh[k];
}

// ---------------------------------------------------------------------------
// K3a: moments. grid = 64 batches x 16 i-slices. Thread t owns bins
// (i = i0+k, j = t), k=0..15.
//   cf[k] = C[i][j]  -> lane-coalesced dword loads (row i, col t)
//   ct[k] = C[j][i]  -> 16 contiguous dwords = 4 uint4 per part
// Linear moments use folded symmetric weights on cf only; energy uses
// cf^2 + cf*ct. Exact u64 integer accumulation; homogeneity via LDS f32
// weight table. Writes 7 doubles per WG.
// ---------------------------------------------------------------------------
__global__ __launch_bounds__(256) void k_moms(const uint32_t* __restrict__ hist,
                                              double* __restrict__ partials,
                                              int nparts) {
    __shared__ float whom[256];
    int b  = blockIdx.x >> 4;
    int sl = blockIdx.x & 15;
    int i0 = sl * 16;
    int t  = threadIdx.x;

    whom[t] = 1.0f / (float)(1 + t * t);
    __syncthreads();

    const uint32_t* h0 = hist + (size_t)b * 65536;
    const uint32_t* h1 = hist + (size_t)(NB + b) * 65536;   // part 1

    uint32_t cf[16], ct[16];
    // ct: contiguous 16 dwords at row t, cols [i0, i0+16)
    {
        const uint4* p0 = (const uint4*)(h0 + t * 256 + i0);
#pragma unroll
        for (int q4 = 0; q4 < 4; ++q4) {
            uint4 v = p0[q4];
            ct[q4 * 4 + 0] = v.x; ct[q4 * 4 + 1] = v.y;
            ct[q4 * 4 + 2] = v.z; ct[q4 * 4 + 3] = v.w;
        }
        if (nparts == 2) {
            const uint4* p1 = (const uint4*)(h1 + t * 256 + i0);
#pragma unroll
            for (int q4 = 0; q4 < 4; ++q4) {
                uint4 v = p1[q4];
                ct[q4 * 4 + 0] += v.x; ct[q4 * 4 + 1] += v.y;
                ct[q4 * 4 + 2] += v.z; ct[q4 * 4 + 3] += v.w;
            }
        }
    }
    // cf: row (i0+k), col t — coalesced across lanes
#pragma unroll
    for (int k = 0; k < 16; ++k) {
        uint32_t v = h0[(i0 + k) * 256 + t];
        if (nparts == 2) v += h1[(i0 + k) * 256 + t];
        cf[k] = v;
    }

    unsigned long long A_con = 0, A_dis = 0, A_e = 0;
    unsigned long long A_s1 = 0, A_s2 = 0, A_sij = 0;
    float A_homf = 0.0f;

#pragma unroll
    for (int k = 0; k < 16; ++k) {
        int i  = i0 + k;
        int j  = t;
        int d  = i - j;
        uint32_t ad = (uint32_t)(d < 0 ? -d : d);
        uint32_t dd = ad * ad;
        uint32_t c  = cf[k];
        A_con += (unsigned long long)c * dd;
        A_dis += (unsigned long long)c * ad;
        A_e   += (unsigned long long)c * c + (unsigned long long)c * ct[k];
        A_s1  += (unsigned long long)c * (uint32_t)(i + j);
        A_s2  += (unsigned long long)c * (uint32_t)(i * i + j * j);
        A_sij += (unsigned long long)c * (uint32_t)(i * j);
        A_homf += (float)c * whom[ad];
    }

    double acc[7] = {(double)A_con, (double)A_dis, (double)A_homf,
                     (double)A_e, (double)A_s1, (double)A_s2, (double)A_sij};
#pragma unroll
    for (int a = 0; a < 7; ++a) {
#pragma unroll
        for (int off = 32; off; off >>= 1)
            acc[a] += __shfl_down(acc[a], off, 64);
    }
    __shared__ double sred[7][4];
    int wid = t >> 6, lane = t & 63;
    if (lane == 0) {
#pragma unroll
        for (int a = 0; a < 7; ++a) sred[a][wid] = acc[a];
    }
    __syncthreads();
    if (t < 7)
        partials[(size_t)blockIdx.x * 7 + t] =
            sred[t][0] + sred[t][1] + sred[t][2] + sred[t][3];
}

// ---------------------------------------------------------------------------
// K3b: final reduce + features. grid = 64, block = 64 (one wave).
// ---------------------------------------------------------------------------
__global__ __launch_bounds__(64) void k_final(const double* __restrict__ partials,
                                              float* __restrict__ out) {
    int b = blockIdx.x;
    int lane = threadIdx.x;

    double v[7];
#pragma unroll
    for (int a = 0; a < 7; ++a) {
        double x = (lane < 16) ? partials[(size_t)(b * 16 + lane) * 7 + a] : 0.0;
#pragma unroll
        for (int off = 8; off; off >>= 1)
            x += __shfl_down(x, off, 64);
        v[a] = x;
    }

    if (lane == 0) {
        const double T = 2.0 * (double)NPAIRS;   // symmetrized total
        double contrast = 2.0 * v[0] / T;
        double dissim   = 2.0 * v[1] / T;
        double homog    = 2.0 * v[2] / T;
        double energy   = sqrt(2.0 * v[3]) / T;
        double mu    = v[4] / T;                 // mu_i == mu_j
        double var   = v[5] / T - mu * mu;       // var_i == var_j
        double cov   = 2.0 * v[6] / T - mu * mu;
        double sd    = sqrt(var * var);
        double corr  = (sd < 1e-15) ? 1.0 : cov / fmax(sd, 1e-15);

        float f[5] = {(float)contrast, (float)dissim, (float)homog,
                      (float)energy, (float)corr};
        float mn = f[0], mx = f[0];
#pragma unroll
        for (int k = 1; k < 5; ++k) { mn = fminf(mn, f[k]); mx = fmaxf(mx, f[k]); }
        float rng = mx - mn;
#pragma unroll
        for (int k = 0; k < 5; ++k) {
            float fn = (f[k] - mn) / rng;
            float q8 = floorf(__fmul_rn(fn, 255.0f));
            float val = q8 / 255.0f;
            out[b * 15 + 0 * 5 + k] = val;
            out[b * 15 + 1 * 5 + k] = val;
            out[b * 15 + 2 * 5 + k] = val;
        }
    }
}

// ---------------------------------------------------------------------------
extern "C" void kernel_launch(void* const* d_in, const int* in_sizes, int n_in,
                              void* d_out, int out_size, void* d_ws, size_t ws_size,
                              hipStream_t stream) {
    const float* img = (const float*)d_in[0];
    float* out = (float*)d_out;

    uint32_t* gray = (uint32_t*)d_ws;                         // 16 MB
    uint32_t* hist = (uint32_t*)((char*)d_ws + ((size_t)1 << 24));

    // gray(16MB) + hist(nparts*16MB) + partials(64*16*7*8 = 57344 B)
    int nparts = (ws_size >= ((size_t)3 << 24) + 65536) ? 2 : 1;
    double* partials = (double*)((char*)d_ws + ((size_t)(1 + nparts) << 24));

    k_gray<<<16384, 256, 0, stream>>>(img, gray);
    k_hist<<<256 * nparts, 256, 0, stream>>>(gray, hist, nparts);
    k_moms<<<NB * 16, 256, 0, stream>>>(hist, partials, nparts);
    k_final<<<NB, 64, 0, stream>>>(partials, out);
}

// Round 4
// 82.898 us; speedup vs baseline: 2.3190x; 1.1165x over previous
//
#include <hip/hip_runtime.h>
#include <stdint.h>

#define NLEV   256
#define DIST   5
#define NB     64
#define NH     512
#define NW     512
#define PLANE  (NH*NW)            // 262144
#define NPAIRS (NH*(NW-DIST))     // 259584
#define NPARTS 4                  // 128 rows/part -> max 64896 pairs/bin < 65536 (u16-safe)

// ---------------------------------------------------------------------------
// K1 (fused gray+hist): grid = 64 batches x 4 parts, 512 threads (8 waves).
// One wave processes one full 512-px row per iteration: lane owns 8 px,
// computes gray indices in registers, gets the col+5 neighbor via __shfl,
// and does ONE packed-u16 LDS atomic per pair. 128KB LDS = full 256x256
// u16 histogram -> no i-filtering, no redundant scan, no gray buffer.
// Output: hist16[part][b][32768 u32 words] (u16 pairs, even bin = low half).
// ---------------------------------------------------------------------------
__global__ __launch_bounds__(512) void k_grayhist(const float* __restrict__ img,
                                                  uint32_t* __restrict__ hist16) {
    __shared__ uint32_t lh[32768];               // 128 KB packed u16 counts
    const int part = blockIdx.x & 3;
    const int b    = blockIdx.x >> 2;
    const int t    = threadIdx.x;
    const int w    = t >> 6;                     // wave 0..7
    const int lane = t & 63;

    {   // zero LDS
        uint4* lh4 = (uint4*)lh;
        for (int k = t; k < 8192; k += 512) lh4[k] = make_uint4(0, 0, 0, 0);
    }
    __syncthreads();

    const int row0 = part * 128;
#pragma unroll 1
    for (int it = 0; it < 16; ++it) {
        const int row = row0 + (it << 3) + w;
        const size_t ibase = ((size_t)(b * 3) * NH + row) * NW;
        const float4* pR = (const float4*)(img + ibase);
        const float4* pG = (const float4*)(img + ibase + PLANE);
        const float4* pB = (const float4*)(img + ibase + 2 * (size_t)PLANE);
        float4 r0 = pR[2 * lane], r1 = pR[2 * lane + 1];
        float4 g0 = pG[2 * lane], g1 = pG[2 * lane + 1];
        float4 b0 = pB[2 * lane], b1 = pB[2 * lane + 1];

        float rr[8] = {r0.x, r0.y, r0.z, r0.w, r1.x, r1.y, r1.z, r1.w};
        float gg[8] = {g0.x, g0.y, g0.z, g0.w, g1.x, g1.y, g1.z, g1.w};
        float bb[8] = {b0.x, b0.y, b0.z, b0.w, b1.x, b1.y, b1.z, b1.w};

        uint32_t gi[8];
#pragma unroll
        for (int k = 0; k < 8; ++k) {
            float qr = fminf(fmaxf(floorf(__fmul_rn(rr[k], 255.0f)), 0.0f), 255.0f);
            float qg = fminf(fmaxf(floorf(__fmul_rn(gg[k], 255.0f)), 0.0f), 255.0f);
            float qb = fminf(fmaxf(floorf(__fmul_rn(bb[k], 255.0f)), 0.0f), 255.0f);
            float gy = __fadd_rn(__fadd_rn(__fmul_rn(0.299f, qr),
                                           __fmul_rn(0.587f, qg)),
                                 __fmul_rn(0.114f, qb));
            int v = (int)rintf(gy);              // round half to even == jnp.round
            gi[k] = (uint32_t)(v < 0 ? 0 : (v > 255 ? 255 : v));
        }
        uint32_t w0 = gi[0] | (gi[1] << 8) | (gi[2] << 16) | (gi[3] << 24);
        uint32_t w1 = gi[4] | (gi[5] << 8) | (gi[6] << 16) | (gi[7] << 24);
        uint32_t nw0 = __shfl(w0, lane + 1, 64); // lane63: unused (np=3)
        uint32_t nw1 = __shfl(w1, lane + 1, 64);
        // j bytes aligned to i position k: col(8*lane+k)+5
        uint32_t jlo = (w1 >> 8) | (nw0 << 24);  // k=0..3
        uint32_t jhi = (nw0 >> 8) | (nw1 << 24); // k=4..7
        const int np = (lane == 63) ? 3 : 8;     // cols <= 506 pair-valid
#pragma unroll
        for (int k = 0; k < 8; ++k) {
            if (k < np) {
                uint32_t j = ((k < 4) ? (jlo >> (8 * k)) : (jhi >> (8 * (k - 4)))) & 255u;
                uint32_t bin = (gi[k] << 8) | j;
                atomicAdd(&lh[bin >> 1], 1u << ((bin & 1u) << 4));
            }
        }
    }
    __syncthreads();

    uint4* dst = (uint4*)(hist16 + (((size_t)(part * NB + b)) << 15));
    const uint4* src = (const uint4*)lh;
    for (int k = t; k < 8192; k += 512) dst[k] = src[k];
}

// ---------------------------------------------------------------------------
// K2: moments. grid = 64 batches x 32 i-slices (8 rows each), 256 threads.
// Thread t owns bins (i = i0+k, j = t), k=0..7, summing 4 u16 parts.
//   cf: coalesced word loads (2 lanes share a word -> broadcast)
//   ct: 1 uint4 per part = 4 consecutive words (energy transpose term)
// Exact u64 integer moments + f32 homogeneity table; 7 doubles per WG.
// ---------------------------------------------------------------------------
__global__ __launch_bounds__(256) void k_moms(const uint32_t* __restrict__ hist16,
                                              double* __restrict__ partials) {
    __shared__ float whom[256];
    const int b  = blockIdx.x >> 5;
    const int sl = blockIdx.x & 31;
    const int i0 = sl * 8;
    const int t  = threadIdx.x;

    whom[t] = 1.0f / (float)(1 + t * t);
    __syncthreads();

    uint32_t cf[8], ct[8];
#pragma unroll
    for (int k = 0; k < 8; ++k) { cf[k] = 0; ct[k] = 0; }

#pragma unroll
    for (int p = 0; p < NPARTS; ++p) {
        const uint32_t* hp = hist16 + (((size_t)(p * NB + b)) << 15);
        const int sh = (t & 1) * 16;
#pragma unroll
        for (int k = 0; k < 8; ++k)
            cf[k] += (hp[(i0 + k) * 128 + (t >> 1)] >> sh) & 0xFFFFu;
        uint4 v = *(const uint4*)(hp + t * 128 + (i0 >> 1));
        ct[0] += v.x & 0xFFFFu; ct[1] += v.x >> 16;
        ct[2] += v.y & 0xFFFFu; ct[3] += v.y >> 16;
        ct[4] += v.z & 0xFFFFu; ct[5] += v.z >> 16;
        ct[6] += v.w & 0xFFFFu; ct[7] += v.w >> 16;
    }

    unsigned long long A_con = 0, A_dis = 0, A_e = 0;
    unsigned long long A_s1 = 0, A_s2 = 0, A_sij = 0;
    float A_homf = 0.0f;

#pragma unroll
    for (int k = 0; k < 8; ++k) {
        int i  = i0 + k;
        int j  = t;
        int d  = i - j;
        uint32_t ad = (uint32_t)(d < 0 ? -d : d);
        uint32_t dd = ad * ad;
        uint32_t c  = cf[k];
        A_con += (unsigned long long)c * dd;
        A_dis += (unsigned long long)c * ad;
        A_e   += (unsigned long long)c * c + (unsigned long long)c * ct[k];
        A_s1  += (unsigned long long)c * (uint32_t)(i + j);
        A_s2  += (unsigned long long)c * (uint32_t)(i * i + j * j);
        A_sij += (unsigned long long)c * (uint32_t)(i * j);
        A_homf += (float)c * whom[ad];
    }

    double acc[7] = {(double)A_con, (double)A_dis, (double)A_homf,
                     (double)A_e, (double)A_s1, (double)A_s2, (double)A_sij};
#pragma unroll
    for (int a = 0; a < 7; ++a) {
#pragma unroll
        for (int off = 32; off; off >>= 1)
            acc[a] += __shfl_down(acc[a], off, 64);
    }
    __shared__ double sred[7][4];
    int wid = t >> 6, lane = t & 63;
    if (lane == 0) {
#pragma unroll
        for (int a = 0; a < 7; ++a) sred[a][wid] = acc[a];
    }
    __syncthreads();
    if (t < 7)
        partials[(size_t)blockIdx.x * 7 + t] =
            sred[t][0] + sred[t][1] + sred[t][2] + sred[t][3];
}

// ---------------------------------------------------------------------------
// K3: final reduce + features. grid = 64, block = 64 (one wave).
// ---------------------------------------------------------------------------
__global__ __launch_bounds__(64) void k_final(const double* __restrict__ partials,
                                              float* __restrict__ out) {
    int b = blockIdx.x;
    int lane = threadIdx.x;

    double v[7];
#pragma unroll
    for (int a = 0; a < 7; ++a) {
        double x = (lane < 32) ? partials[(size_t)(b * 32 + lane) * 7 + a] : 0.0;
#pragma unroll
        for (int off = 32; off; off >>= 1)
            x += __shfl_down(x, off, 64);
        v[a] = x;
    }

    if (lane == 0) {
        const double T = 2.0 * (double)NPAIRS;   // symmetrized total
        double contrast = 2.0 * v[0] / T;
        double dissim   = 2.0 * v[1] / T;
        double homog    = 2.0 * v[2] / T;
        double energy   = sqrt(2.0 * v[3]) / T;
        double mu    = v[4] / T;                 // mu_i == mu_j (symmetric)
        double var   = v[5] / T - mu * mu;
        double cov   = 2.0 * v[6] / T - mu * mu;
        double sd    = sqrt(var * var);
        double corr  = (sd < 1e-15) ? 1.0 : cov / fmax(sd, 1e-15);

        float f[5] = {(float)contrast, (float)dissim, (float)homog,
                      (float)energy, (float)corr};
        float mn = f[0], mx = f[0];
#pragma unroll
        for (int k = 1; k < 5; ++k) { mn = fminf(mn, f[k]); mx = fmaxf(mx, f[k]); }
        float rng = mx - mn;
#pragma unroll
        for (int k = 0; k < 5; ++k) {
            float fn = (f[k] - mn) / rng;
            float q8 = floorf(__fmul_rn(fn, 255.0f));
            float val = q8 / 255.0f;
            out[b * 15 + 0 * 5 + k] = val;
            out[b * 15 + 1 * 5 + k] = val;
            out[b * 15 + 2 * 5 + k] = val;
        }
    }
}

// ---------------------------------------------------------------------------
extern "C" void kernel_launch(void* const* d_in, const int* in_sizes, int n_in,
                              void* d_out, int out_size, void* d_ws, size_t ws_size,
                              hipStream_t stream) {
    const float* img = (const float*)d_in[0];
    float* out = (float*)d_out;

    // hist16: 4 parts x 64 b x 128KB = 32 MB; partials after (2048*7*8 = 114KB)
    uint32_t* hist16 = (uint32_t*)d_ws;
    double* partials = (double*)((char*)d_ws + ((size_t)32 << 20));

    k_grayhist<<<NB * NPARTS, 512, 0, stream>>>(img, hist16);
    k_moms<<<NB * 32, 256, 0, stream>>>(hist16, partials);
    k_final<<<NB, 64, 0, stream>>>(partials, out);
}